// Round 3
// baseline (270.209 us; speedup 1.0000x reference)
//
#include <hip/hip_runtime.h>
#include <hip/hip_bf16.h>

// B=4, S=2048, D=1024.  M = B*S = 8192.
// Workspace layout (bytes):
//   [0,         33554432)  : E bf16 (4*2048*2048) = exp(scores)
//     overlay (dead before qk runs):
//     [0,         16777216) : Xb  bf16 (8192*1024)
//     [16777216,  23068672) : Wt  bf16 (3072*1024)
//   [50331648,  50364416)  : rowsum fp32 (8192)   (zeroed by setup)
//   [67108864,  83886080)  : Q bf16 (8192*1024)
//   [83886080, 100663296)  : K bf16 (8192*1024)
//   [100663296,117440512)  : Vt bf16 (4*1024*2048) -- written DIRECTLY by qkv
//
// R10 rationale: R1 (latency pipelining depth-2) NULL, R2 (traffic halving)
// NULL, yet MfmaUtil 13%, HBM 12%, VALU 21% -- nothing saturated.  The loud
// counter: FETCH_SIZE ~= full Q+K every round: reads of freshly-written data
// come from HBM/coherence, i.e. Q/K are DIRTY in other XCDs' L2s after qkv;
// cross-XCD dirty-line resolution makes per-iter load latency huge, and the
// vmcnt(0)-drain core pays it every K-step.  Fixes:
//   (a) nontemporal stores for all producer->consumer tensors (Q,K,Vt,E,
//       Xb,Wt,out): stream past L2 so consumers read clean L3 lines.
//   (b) qk/pv use gemm_core_p3: 128x128 tile, BK=32, TRIPLE-buffered LDS
//       (48KB, 3 blocks/CU), counted vmcnt(8) + raw s_barrier -- no
//       vmcnt(0) drain in steady state; stages it+1,it+2 stay in flight
//       across barriers (T3/T4).  sched_barrier(0) fences per rule #18.

typedef __attribute__((ext_vector_type(8))) short short8;
typedef __attribute__((ext_vector_type(4))) short s16x4;
typedef __attribute__((ext_vector_type(4))) float f32x4;

__device__ __forceinline__ short f2bf(float f) {
  __hip_bfloat16 h = __float2bfloat16(f);
  return *reinterpret_cast<short*>(&h);
}

__device__ __forceinline__ void gll16(const void* g, void* l) {
  __builtin_amdgcn_global_load_lds((const __attribute__((address_space(1))) void*)g,
                                   (__attribute__((address_space(3))) void*)l,
                                   16, 0, 0);
}

__device__ __forceinline__ void ntst_s(short* p, short v)   { __builtin_nontemporal_store(v, p); }
__device__ __forceinline__ void ntst_s4(s16x4* p, s16x4 v)  { __builtin_nontemporal_store(v, p); }
__device__ __forceinline__ void ntst_f(float* p, float v)   { __builtin_nontemporal_store(v, p); }

// ---------------------------------------------------------------------------
// 128x128-tile GEMM core, BK=64, 4 waves, drain-style (qkv only -- proven
// 780 TF there).  XOR bank swizzle on 16B k-groups.
// ---------------------------------------------------------------------------
__device__ __forceinline__ void gemm_core(const short* __restrict__ A,
                                          const short* __restrict__ Bt,
                                          int lda, int ldb,
                                          int row0, int col0, int kIters,
                                          f32x4 acc[4][4],
                                          short* lA, short* lB) {
  const int tid  = threadIdx.x;
  const int wave = tid >> 6;
  const int lane = tid & 63;
  const int quad = lane >> 4;
  const int l16  = lane & 15;

  const f32x4 zero = {0.f, 0.f, 0.f, 0.f};
#pragma unroll
  for (int i = 0; i < 4; ++i)
#pragma unroll
    for (int j = 0; j < 4; ++j) acc[i][j] = zero;

  const int srow = tid >> 3;                    // 0..31
  const int gcol = ((tid & 7) ^ (srow & 7)) * 8;
  const short* A1 = A + (size_t)(row0 + srow) * lda + gcol;
  const short* A2 = A + (size_t)(row0 + srow + 32) * lda + gcol;
  const short* A3 = A + (size_t)(row0 + srow + 64) * lda + gcol;
  const short* A4 = A + (size_t)(row0 + srow + 96) * lda + gcol;
  const short* B1 = Bt + (size_t)(col0 + srow) * ldb + gcol;
  const short* B2 = Bt + (size_t)(col0 + srow + 32) * ldb + gcol;
  const short* B3 = Bt + (size_t)(col0 + srow + 64) * ldb + gcol;
  const short* B4 = Bt + (size_t)(col0 + srow + 96) * ldb + gcol;

  short* lA1 = lA + wave * 512;
  short* lA2 = lA + 2048 + wave * 512;
  short* lA3 = lA + 4096 + wave * 512;
  short* lA4 = lA + 6144 + wave * 512;
  short* lB1 = lB + wave * 512;
  short* lB2 = lB + 2048 + wave * 512;
  short* lB3 = lB + 4096 + wave * 512;
  short* lB4 = lB + 6144 + wave * 512;

  const int rswz  = l16 & 7;
  const int slot0 = (quad ^ rswz) * 8;
  const int slot1 = ((4 + quad) ^ rswz) * 8;
  const short* aRow = lA + ((wave >> 1) * 64 + l16) * 64;
  const short* bRow = lB + ((wave & 1) * 64 + l16) * 64;

  for (int it = 0; it < kIters; ++it) {
    const int k0 = it * 64;
    gll16(A1 + k0, lA1);
    gll16(A2 + k0, lA2);
    gll16(A3 + k0, lA3);
    gll16(A4 + k0, lA4);
    gll16(B1 + k0, lB1);
    gll16(B2 + k0, lB2);
    gll16(B3 + k0, lB3);
    gll16(B4 + k0, lB4);
    __syncthreads();

#pragma unroll
    for (int s = 0; s < 2; ++s) {
      const int so = s ? slot1 : slot0;
      short8 af[4], bfr[4];
#pragma unroll
      for (int i = 0; i < 4; ++i) af[i] = *(const short8*)(aRow + i * 1024 + so);
#pragma unroll
      for (int j = 0; j < 4; ++j) bfr[j] = *(const short8*)(bRow + j * 1024 + so);
#pragma unroll
      for (int i = 0; i < 4; ++i)
#pragma unroll
        for (int j = 0; j < 4; ++j)
          acc[i][j] = __builtin_amdgcn_mfma_f32_16x16x32_bf16(af[i], bfr[j], acc[i][j], 0, 0, 0);
    }
    __syncthreads();
  }
}

// ---------------------------------------------------------------------------
// 128x128-tile GEMM core, BK=32, 4 waves, TRIPLE-buffered, counted vmcnt.
// LDS = 3 stages x 16KB (A 128x32 = 8KB + B 128x32 = 8KB).  Per stage each
// thread issues 4 gll16 (A rows srow/srow+64, B rows srow/srow+64), so a
// wave has 4 vmcnt entries per stage; depth-3 ring => steady-state wait is
// vmcnt(8) (stages it+1, it+2 stay IN FLIGHT across the barriers).
// XOR swizzle: row r's 16B k-group g stored at slot g ^ (r&3) (pre-swizzled
// global source, linear LDS dest -- rule #21).  Fragment read undoes it.
// Per iter:
//   vmcnt(8) ; sched_barrier ; s_barrier      <- stage it ready (all waves)
//   8x ds_read_b128 fragments of stage it
//   lgkmcnt(0) ; sched_barrier ; s_barrier    <- slot free for reuse
//   issue stage it+3 into slot (it%3)
//   16x MFMA
// ---------------------------------------------------------------------------
__device__ __forceinline__ void gemm_core_p3(const short* __restrict__ A,
                                             const short* __restrict__ Bt,
                                             int lda, int ldb,
                                             int row0, int col0, int kIters,
                                             f32x4 acc[4][4], short* lds) {
  const int tid  = threadIdx.x;
  const int wave = tid >> 6;
  const int lane = tid & 63;
  const int quad = lane >> 4;
  const int l16  = lane & 15;

  const f32x4 zero = {0.f, 0.f, 0.f, 0.f};
#pragma unroll
  for (int i = 0; i < 4; ++i)
#pragma unroll
    for (int j = 0; j < 4; ++j) acc[i][j] = zero;

  // staging: thread t -> row srow = t>>2 (0..63; +64 for second call),
  // k-group slot (t&3); global source pre-swizzled by ^(row&3).
  const int srow = tid >> 2;
  const int gcol = ((tid & 3) ^ (srow & 3)) * 8;
  const short* Ag = A  + (size_t)(row0 + srow) * lda + gcol;
  const short* Bg = Bt + (size_t)(col0 + srow) * ldb + gcol;
  const size_t a64 = (size_t)64 * lda;
  const size_t b64 = (size_t)64 * ldb;

  // fragment read offsets (shorts, within a 8192-short stage):
  // A row r = rb + i*16 + l16, global k-group = quad at slot quad^(r&3);
  // r&3 == l16&3 for all i since rb, 16i are multiples of 4.
  const int rb = (wave >> 1) * 64;
  const int cb = (wave & 1) * 64;
  const int slot = (quad ^ (l16 & 3)) * 8;
  const int aoff = (rb + l16) * 32 + slot;
  const int boff = 4096 + (cb + l16) * 32 + slot;

#define P3_ISSUE(sl, itv) do {                        \
    short* st_ = lds + (sl) * 8192 + wave * 512;      \
    const int k0_ = (itv) * 32;                       \
    gll16(Ag + k0_,        st_);                      \
    gll16(Ag + a64 + k0_,  st_ + 2048);               \
    gll16(Bg + k0_,        st_ + 4096);               \
    gll16(Bg + b64 + k0_,  st_ + 6144);               \
  } while (0)

  // prologue: stages 0,1,2 in flight (12 loads/wave)
  P3_ISSUE(0, 0);
  P3_ISSUE(1, 1);
  P3_ISSUE(2, 2);

  int s = 0;
  for (int it = 0; it < kIters; ++it) {
    if (it < kIters - 2)       asm volatile("s_waitcnt vmcnt(8)" ::: "memory");
    else if (it == kIters - 2) asm volatile("s_waitcnt vmcnt(4)" ::: "memory");
    else                       asm volatile("s_waitcnt vmcnt(0)" ::: "memory");
    __builtin_amdgcn_sched_barrier(0);
    __builtin_amdgcn_s_barrier();      // all waves' stage-it loads landed

    const short* st = lds + s * 8192;
    short8 af[4], bfr[4];
#pragma unroll
    for (int i = 0; i < 4; ++i) af[i]  = *(const short8*)(st + aoff + i * 512);
#pragma unroll
    for (int j = 0; j < 4; ++j) bfr[j] = *(const short8*)(st + boff + j * 512);

    asm volatile("s_waitcnt lgkmcnt(0)" ::: "memory");
    __builtin_amdgcn_sched_barrier(0);
    __builtin_amdgcn_s_barrier();      // all waves done reading slot s

    if (it + 3 < kIters) P3_ISSUE(s, it + 3);
    __builtin_amdgcn_sched_barrier(0);

#pragma unroll
    for (int i = 0; i < 4; ++i)
#pragma unroll
      for (int j = 0; j < 4; ++j)
        acc[i][j] = __builtin_amdgcn_mfma_f32_16x16x32_bf16(af[i], bfr[j], acc[i][j], 0, 0, 0);

    s = (s == 2) ? 0 : s + 1;
  }
#undef P3_ISSUE
}

// C/D layout: row = quad*4 + reg, col = l16  (verified m89)
#define EPILOGUE_VARS                         \
  const int lane = threadIdx.x & 63;          \
  const int wave = threadIdx.x >> 6;          \
  const int quad = lane >> 4;                 \
  const int l16  = lane & 15;                 \
  const int rb   = (wave >> 1) * 64;          \
  const int cb   = (wave & 1) * 64;

// ---------------------------------------------------------------------------
// setup: blocks [0,8192) cast X->Xb; [8192,11264) transpose W->Wt;
//        [11264,11272) zero rowsum.
__global__ __launch_bounds__(256) void setup_kernel(const float* __restrict__ X,
                                                    const float* __restrict__ W,
                                                    short* __restrict__ Xb,
                                                    short* __restrict__ Wt,
                                                    float* __restrict__ rs) {
  const int bid = blockIdx.x;
  if (bid < 8192) {
    const int i = (bid * 256 + threadIdx.x) * 4;
    const f32x4 v = *(const f32x4*)(X + i);
    s16x4 o;
    o.x = f2bf(v.x); o.y = f2bf(v.y); o.z = f2bf(v.z); o.w = f2bf(v.w);
    ntst_s4((s16x4*)(Xb + i), o);
  } else if (bid < 11264) {
    __shared__ float tile[32][33];
    const int r  = bid - 8192;
    const int ni = r % 96;
    const int ki = r / 96;
    const int tx = threadIdx.x & 31;
    const int ty = threadIdx.x >> 5;
#pragma unroll
    for (int rr = 0; rr < 4; ++rr)
      tile[ty + rr * 8][tx] = W[(size_t)(ki * 32 + ty + rr * 8) * 3072 + ni * 32 + tx];
    __syncthreads();
#pragma unroll
    for (int rr = 0; rr < 4; ++rr)
      ntst_s(&Wt[(size_t)(ni * 32 + ty + rr * 8) * 1024 + ki * 32 + tx],
             f2bf(tile[tx][ty + rr * 8]));
  } else {
    const int i = (bid - 11264) * 1024 + threadIdx.x * 4;
    const f32x4 zero = {0.f, 0.f, 0.f, 0.f};
    *(f32x4*)(rs + i) = zero;
  }
}

// QKV: [8192x1024] x Wt[3072x1024]^T.  Q,K row-major [s][d]; V-columns
// written DIRECTLY transposed into Vt[b][d][s].  All outputs nontemporal
// so qk/pv read clean lines instead of cross-XCD dirty ones.
__global__ __launch_bounds__(256) void qkv_gemm_kernel(const short* __restrict__ Xb,
                                                       const short* __restrict__ Wt,
                                                       short* __restrict__ Q,
                                                       short* __restrict__ K,
                                                       short* __restrict__ Vt,
                                                       int br0) {
  __shared__ short lA[8192], lB[8192];
  const int br = br0 + blockIdx.x / 24;
  const int bc = blockIdx.x % 24;
  f32x4 acc[4][4];
  gemm_core(Xb, Wt, 1024, 1024, br * 128, bc * 128, 16, acc, lA, lB);

  EPILOGUE_VARS
  const int rbase = br * 128 + rb;
  const int cbase = bc * 128 + cb;
  if (bc < 16) {
#pragma unroll
    for (int i = 0; i < 4; ++i)
#pragma unroll
      for (int j = 0; j < 4; ++j) {
        const int col = cbase + j * 16 + l16;
        short* dst = (col < 1024) ? Q : K;
        const int n = col & 1023;
#pragma unroll
        for (int r = 0; r < 4; ++r) {
          const int row = rbase + i * 16 + quad * 4 + r;
          ntst_s(&dst[(size_t)row * 1024 + n], f2bf(acc[i][j][r]));
        }
      }
  } else {
    const int b  = rbase >> 11;
    const int s0 = rbase & 2047;
    short* VtB = Vt + (size_t)b * 1024 * 2048;
#pragma unroll
    for (int i = 0; i < 4; ++i) {
      const int sb = s0 + i * 16 + quad * 4;
#pragma unroll
      for (int j = 0; j < 4; ++j) {
        const int d = cbase - 2048 + j * 16 + l16;
        s16x4 pk;
        pk.x = f2bf(acc[i][j][0]);
        pk.y = f2bf(acc[i][j][1]);
        pk.z = f2bf(acc[i][j][2]);
        pk.w = f2bf(acc[i][j][3]);
        ntst_s4((s16x4*)(VtB + (size_t)d * 2048 + sb), pk);
      }
    }
  }
}

// qk: 128x128 tiles, 4-wave pipelined core.  E = exp(QK^T/32) + rowsum
// atomics.  Row-tile qi needs k-tiles 0..qi; diagonal masks col>row.
// 136 tiles/batch x 4 = 544 blocks, qi descending (equal cost; ordering
// only affects L2/L3 reuse).  E stores nontemporal (consumed by pv).
__global__ __launch_bounds__(256) void qk_kernel(const short* __restrict__ Q,
                                                 const short* __restrict__ K,
                                                 short* __restrict__ E,
                                                 float* __restrict__ rs) {
  __shared__ short lds[24576];   // 48KB: 3 stages x (A 8KB + B 8KB)
  const int t = blockIdx.x >> 2;   // 0..135
  const int b = blockIdx.x & 3;
  int qi = 15, off = t;
  while (off >= qi + 1) { off -= qi + 1; qi--; }
  const int ki = off;

  f32x4 acc[4][4];
  const short* Qb = Q + (size_t)b * 2048 * 1024;
  const short* Kb = K + (size_t)b * 2048 * 1024;
  gemm_core_p3(Qb, Kb, 1024, 1024, qi * 128, ki * 128, 32, acc, lds);

  EPILOGUE_VARS
  short* Eb  = E + (size_t)b * 2048 * 2048;
  float* rsb = rs + b * 2048;
  const int rbase = qi * 128 + rb;
  const int cbase = ki * 128 + cb;
  const bool diag = (ki == qi);
#pragma unroll
  for (int i = 0; i < 4; ++i)
#pragma unroll
    for (int r = 0; r < 4; ++r) {
      const int row = rbase + i * 16 + quad * 4 + r;
      float partial = 0.f;
#pragma unroll
      for (int j = 0; j < 4; ++j) {
        const int col = cbase + j * 16 + l16;
        float e = __expf(acc[i][j][r] * 0.03125f);
        if (diag && col > row) e = 0.f;
        partial += e;
        ntst_s(&Eb[(size_t)row * 2048 + col], f2bf(e));
      }
      partial += __shfl_xor(partial, 1);
      partial += __shfl_xor(partial, 2);
      partial += __shfl_xor(partial, 4);
      partial += __shfl_xor(partial, 8);
      if (l16 == 0) atomicAdd(rsb + row, partial);
    }
}

// pv: 128x128 out tiles, 4-wave pipelined core.  out = (E x V)/rowsum.
// K-extent per row-tile qi is (qi+1)*128 (causal) -> kIters=(qi+1)*4 at
// BK=32.  16 qi x 8 dj x 4 b = 512 blocks, heavy rows (qi=15) first.
__global__ __launch_bounds__(256) void pv_kernel(const short* __restrict__ E,
                                                 const short* __restrict__ Vt,
                                                 const float* __restrict__ rs,
                                                 float* __restrict__ out) {
  __shared__ short lds[24576];
  const int t   = blockIdx.x;      // 0..511
  const int b   = t >> 7;          // 0..3
  const int rem = t & 127;
  const int qi  = 15 - (rem >> 3); // heavy first
  const int dj  = rem & 7;

  f32x4 acc[4][4];
  const short* Eb  = E + (size_t)b * 2048 * 2048;
  const short* Vtb = Vt + (size_t)b * 1024 * 2048;
  gemm_core_p3(Eb, Vtb, 2048, 2048, qi * 128, dj * 128, (qi + 1) * 4, acc, lds);

  EPILOGUE_VARS
  float* ob = out + (size_t)b * 2048 * 1024;
  const float* rsb = rs + b * 2048;
  const int rbase = qi * 128 + rb;
  const int cbase = dj * 128 + cb;
#pragma unroll
  for (int i = 0; i < 4; ++i)
#pragma unroll
    for (int r2 = 0; r2 < 4; ++r2) {
      const int row = rbase + i * 16 + quad * 4 + r2;
      const float inv = 1.f / rsb[row];
#pragma unroll
      for (int j = 0; j < 4; ++j) {
        const int col = cbase + j * 16 + l16;
        ntst_f(&ob[(size_t)row * 1024 + col], acc[i][j][r2] * inv);
      }
    }
}

// ---------------------------------------------------------------------------
extern "C" void kernel_launch(void* const* d_in, const int* in_sizes, int n_in,
                              void* d_out, int out_size, void* d_ws, size_t ws_size,
                              hipStream_t stream) {
  const float* X = (const float*)d_in[0];
  const float* W = (const float*)d_in[1];
  float* out = (float*)d_out;
  char* w = (char*)d_ws;

  short* Xb = (short*)(w + 0);
  short* Wt = (short*)(w + 16777216);
  short* E  = (short*)(w + 0);          // overlays Xb,Wt (dead after qkv)
  float* rs = (float*)(w + 50331648);
  short* Q  = (short*)(w + 67108864);
  short* K  = (short*)(w + 83886080);
  short* Vt = (short*)(w + 100663296);

  hipLaunchKernelGGL(setup_kernel,    dim3(11272), dim3(256), 0, stream, X, W, Xb, Wt, rs);
  hipLaunchKernelGGL(qkv_gemm_kernel, dim3(768),   dim3(256), 0, stream, Xb, Wt, Q, K, Vt, 0);
  hipLaunchKernelGGL(qkv_gemm_kernel, dim3(768),   dim3(256), 0, stream, Xb, Wt, Q, K, Vt, 32);
  hipLaunchKernelGGL(qk_kernel,       dim3(544),   dim3(256), 0, stream, Q, K, E, rs);
  hipLaunchKernelGGL(pv_kernel,       dim3(512),   dim3(256), 0, stream, E, Vt, rs, out);
}

// Round 4
// 248.267 us; speedup vs baseline: 1.0884x; 1.0884x over previous
//
#include <hip/hip_runtime.h>
#include <hip/hip_bf16.h>

// B=4, S=2048, D=1024.  M = B*S = 8192.
// Workspace layout (bytes):
//   [0,         33554432)  : E bf16 (4*2048*2048) = exp(scores)
//     overlay (dead before qk runs):
//     [0,         16777216) : Xb  bf16 (8192*1024)
//     [16777216,  23068672) : Wt  bf16 (3072*1024)
//   [50331648,  50364416)  : rowsum fp32 (8192)   (zeroed by setup)
//   [67108864,  83886080)  : Q bf16 (8192*1024)
//   [83886080, 100663296)  : K bf16 (8192*1024)
//   [100663296,117440512)  : Vt bf16 (4*1024*2048) -- written DIRECTLY by qkv
//
// Pipeline (4 launches):
//   setup  : cast X->bf16, transpose W->Wt bf16, zero rowsum
//   qkv    : single 1536-block dispatch, 128x128 4-wave drain core (~780TF)
//   qk     : 64x128 tiles, 4-wave drain core, 1088 blocks (4.25/CU)
//   pv     : 64x128 tiles, 4-wave drain core, 1024 blocks (4/CU)
//
// R11 rationale: R3 regressed (NT-E pushed pv to 78MB HBM fetch @2TB/s;
// p3-core slot formula was a 4-way bank conflict, 2.2M cycles).  Reverted
// both.  Durable fact: identical drain core runs 780 TF in qkv (3 blocks/CU)
// but ~380 TF in qk (2.125/CU) -- latency cover comes from co-resident
// blocks (m114), and qk/pv are GRID-limited, not resource-limited.  Fix:
// halve tiles to 64x128 -> 1088/1024 blocks = 4+/CU, 24KB LDS (6 fit).
// Per-block traffic +1.4x is cache-absorbed (R2 proved traffic isn't the
// wall).  Swizzle stays in the proven quad^(l16&7) family (2-way = free).

typedef __attribute__((ext_vector_type(8))) short short8;
typedef __attribute__((ext_vector_type(4))) short s16x4;
typedef __attribute__((ext_vector_type(4))) float f32x4;

__device__ __forceinline__ short f2bf(float f) {
  __hip_bfloat16 h = __float2bfloat16(f);
  return *reinterpret_cast<short*>(&h);
}

__device__ __forceinline__ void gll16(const void* g, void* l) {
  __builtin_amdgcn_global_load_lds((const __attribute__((address_space(1))) void*)g,
                                   (__attribute__((address_space(3))) void*)l,
                                   16, 0, 0);
}

__device__ __forceinline__ void ntst_f(float* p, float v) { __builtin_nontemporal_store(v, p); }

// ---------------------------------------------------------------------------
// 128x128-tile GEMM core, BK=64, 4 waves (qkv).  XOR bank swizzle on 16B
// k-groups (conflicts measured 0).
// ---------------------------------------------------------------------------
__device__ __forceinline__ void gemm_core(const short* __restrict__ A,
                                          const short* __restrict__ Bt,
                                          int lda, int ldb,
                                          int row0, int col0, int kIters,
                                          f32x4 acc[4][4],
                                          short* lA, short* lB) {
  const int tid  = threadIdx.x;
  const int wave = tid >> 6;
  const int lane = tid & 63;
  const int quad = lane >> 4;
  const int l16  = lane & 15;

  const f32x4 zero = {0.f, 0.f, 0.f, 0.f};
#pragma unroll
  for (int i = 0; i < 4; ++i)
#pragma unroll
    for (int j = 0; j < 4; ++j) acc[i][j] = zero;

  const int srow = tid >> 3;                    // 0..31
  const int gcol = ((tid & 7) ^ (srow & 7)) * 8;
  const short* A1 = A + (size_t)(row0 + srow) * lda + gcol;
  const short* A2 = A + (size_t)(row0 + srow + 32) * lda + gcol;
  const short* A3 = A + (size_t)(row0 + srow + 64) * lda + gcol;
  const short* A4 = A + (size_t)(row0 + srow + 96) * lda + gcol;
  const short* B1 = Bt + (size_t)(col0 + srow) * ldb + gcol;
  const short* B2 = Bt + (size_t)(col0 + srow + 32) * ldb + gcol;
  const short* B3 = Bt + (size_t)(col0 + srow + 64) * ldb + gcol;
  const short* B4 = Bt + (size_t)(col0 + srow + 96) * ldb + gcol;

  short* lA1 = lA + wave * 512;
  short* lA2 = lA + 2048 + wave * 512;
  short* lA3 = lA + 4096 + wave * 512;
  short* lA4 = lA + 6144 + wave * 512;
  short* lB1 = lB + wave * 512;
  short* lB2 = lB + 2048 + wave * 512;
  short* lB3 = lB + 4096 + wave * 512;
  short* lB4 = lB + 6144 + wave * 512;

  const int rswz  = l16 & 7;
  const int slot0 = (quad ^ rswz) * 8;
  const int slot1 = ((4 + quad) ^ rswz) * 8;
  const short* aRow = lA + ((wave >> 1) * 64 + l16) * 64;
  const short* bRow = lB + ((wave & 1) * 64 + l16) * 64;

  for (int it = 0; it < kIters; ++it) {
    const int k0 = it * 64;
    gll16(A1 + k0, lA1);
    gll16(A2 + k0, lA2);
    gll16(A3 + k0, lA3);
    gll16(A4 + k0, lA4);
    gll16(B1 + k0, lB1);
    gll16(B2 + k0, lB2);
    gll16(B3 + k0, lB3);
    gll16(B4 + k0, lB4);
    __syncthreads();

#pragma unroll
    for (int s = 0; s < 2; ++s) {
      const int so = s ? slot1 : slot0;
      short8 af[4], bfr[4];
#pragma unroll
      for (int i = 0; i < 4; ++i) af[i] = *(const short8*)(aRow + i * 1024 + so);
#pragma unroll
      for (int j = 0; j < 4; ++j) bfr[j] = *(const short8*)(bRow + j * 1024 + so);
#pragma unroll
      for (int i = 0; i < 4; ++i)
#pragma unroll
        for (int j = 0; j < 4; ++j)
          acc[i][j] = __builtin_amdgcn_mfma_f32_16x16x32_bf16(af[i], bfr[j], acc[i][j], 0, 0, 0);
    }
    __syncthreads();
  }
}

// ---------------------------------------------------------------------------
// 64x128-tile GEMM core, BK=64, 4 waves (qk/pv).  All waves share the 64
// A-rows; wave w owns output cols [w*32, w*32+32) -> acc[4][2].
// LDS: A 64x64 (8KB, 2 regions of 32 rows) + B 128x64 (16KB, 4 regions).
// Same proven swizzle: row r stores k-group g at slot g^(r&7) via the
// pre-swizzled global source; fragment read undoes it (2-way = free).
// ---------------------------------------------------------------------------
__device__ __forceinline__ void gemm_core64(const short* __restrict__ A,
                                            const short* __restrict__ Bt,
                                            int lda, int ldb,
                                            int row0, int col0, int kIters,
                                            f32x4 acc[4][2],
                                            short* lA, short* lB) {
  const int tid  = threadIdx.x;
  const int wave = tid >> 6;
  const int lane = tid & 63;
  const int quad = lane >> 4;
  const int l16  = lane & 15;

  const f32x4 zero = {0.f, 0.f, 0.f, 0.f};
#pragma unroll
  for (int i = 0; i < 4; ++i)
#pragma unroll
    for (int j = 0; j < 2; ++j) acc[i][j] = zero;

  const int srow = tid >> 3;                    // 0..31
  const int gcol = ((tid & 7) ^ (srow & 7)) * 8;
  const short* A1 = A + (size_t)(row0 + srow) * lda + gcol;
  const short* A2 = A + (size_t)(row0 + srow + 32) * lda + gcol;
  const short* B1 = Bt + (size_t)(col0 + srow) * ldb + gcol;
  const short* B2 = Bt + (size_t)(col0 + srow + 32) * ldb + gcol;
  const short* B3 = Bt + (size_t)(col0 + srow + 64) * ldb + gcol;
  const short* B4 = Bt + (size_t)(col0 + srow + 96) * ldb + gcol;

  // staging dests: per-thread linear tid*8 within each 2048-short region
  short* lA1 = lA + wave * 512;
  short* lA2 = lA + 2048 + wave * 512;
  short* lB1 = lB + wave * 512;
  short* lB2 = lB + 2048 + wave * 512;
  short* lB3 = lB + 4096 + wave * 512;
  short* lB4 = lB + 6144 + wave * 512;

  const int rswz  = l16 & 7;
  const int slot0 = (quad ^ rswz) * 8;
  const int slot1 = ((4 + quad) ^ rswz) * 8;
  const short* aRow = lA + l16 * 64;                 // rows i*16+l16, all waves
  const short* bRow = lB + (wave * 32 + l16) * 64;   // rows wave*32+j*16+l16

  for (int it = 0; it < kIters; ++it) {
    const int k0 = it * 64;
    gll16(A1 + k0, lA1);
    gll16(A2 + k0, lA2);
    gll16(B1 + k0, lB1);
    gll16(B2 + k0, lB2);
    gll16(B3 + k0, lB3);
    gll16(B4 + k0, lB4);
    __syncthreads();

#pragma unroll
    for (int s = 0; s < 2; ++s) {
      const int so = s ? slot1 : slot0;
      short8 af[4], bfr[2];
#pragma unroll
      for (int i = 0; i < 4; ++i) af[i] = *(const short8*)(aRow + i * 1024 + so);
#pragma unroll
      for (int j = 0; j < 2; ++j) bfr[j] = *(const short8*)(bRow + j * 1024 + so);
#pragma unroll
      for (int i = 0; i < 4; ++i)
#pragma unroll
        for (int j = 0; j < 2; ++j)
          acc[i][j] = __builtin_amdgcn_mfma_f32_16x16x32_bf16(af[i], bfr[j], acc[i][j], 0, 0, 0);
    }
    __syncthreads();
  }
}

// C/D layout: row = quad*4 + reg, col = l16  (verified m89)
#define EPILOGUE_VARS                         \
  const int lane = threadIdx.x & 63;          \
  const int wave = threadIdx.x >> 6;          \
  const int quad = lane >> 4;                 \
  const int l16  = lane & 15;                 \
  const int rb   = (wave >> 1) * 64;          \
  const int cb   = (wave & 1) * 64;

// ---------------------------------------------------------------------------
// setup: blocks [0,8192) cast X->Xb; [8192,11264) transpose W->Wt;
//        [11264,11272) zero rowsum.
__global__ __launch_bounds__(256) void setup_kernel(const float* __restrict__ X,
                                                    const float* __restrict__ W,
                                                    short* __restrict__ Xb,
                                                    short* __restrict__ Wt,
                                                    float* __restrict__ rs) {
  const int bid = blockIdx.x;
  if (bid < 8192) {
    const int i = (bid * 256 + threadIdx.x) * 4;
    const f32x4 v = *(const f32x4*)(X + i);
    s16x4 o;
    o.x = f2bf(v.x); o.y = f2bf(v.y); o.z = f2bf(v.z); o.w = f2bf(v.w);
    *(s16x4*)(Xb + i) = o;
  } else if (bid < 11264) {
    __shared__ float tile[32][33];
    const int r  = bid - 8192;
    const int ni = r % 96;
    const int ki = r / 96;
    const int tx = threadIdx.x & 31;
    const int ty = threadIdx.x >> 5;
#pragma unroll
    for (int rr = 0; rr < 4; ++rr)
      tile[ty + rr * 8][tx] = W[(size_t)(ki * 32 + ty + rr * 8) * 3072 + ni * 32 + tx];
    __syncthreads();
#pragma unroll
    for (int rr = 0; rr < 4; ++rr)
      Wt[(size_t)(ni * 32 + ty + rr * 8) * 1024 + ki * 32 + tx] = f2bf(tile[tx][ty + rr * 8]);
  } else {
    const int i = (bid - 11264) * 1024 + threadIdx.x * 4;
    const f32x4 zero = {0.f, 0.f, 0.f, 0.f};
    *(f32x4*)(rs + i) = zero;
  }
}

// QKV: [8192x1024] x Wt[3072x1024]^T, single 1536-block dispatch.
// Q,K row-major [s][d]; V-columns written transposed into Vt[b][d][s].
__global__ __launch_bounds__(256) void qkv_gemm_kernel(const short* __restrict__ Xb,
                                                       const short* __restrict__ Wt,
                                                       short* __restrict__ Q,
                                                       short* __restrict__ K,
                                                       short* __restrict__ Vt) {
  __shared__ short lA[8192], lB[8192];
  const int br = blockIdx.x / 24;
  const int bc = blockIdx.x % 24;
  f32x4 acc[4][4];
  gemm_core(Xb, Wt, 1024, 1024, br * 128, bc * 128, 16, acc, lA, lB);

  EPILOGUE_VARS
  const int rbase = br * 128 + rb;
  const int cbase = bc * 128 + cb;
  if (bc < 16) {
#pragma unroll
    for (int i = 0; i < 4; ++i)
#pragma unroll
      for (int j = 0; j < 4; ++j) {
        const int col = cbase + j * 16 + l16;
        short* dst = (col < 1024) ? Q : K;
        const int n = col & 1023;
#pragma unroll
        for (int r = 0; r < 4; ++r) {
          const int row = rbase + i * 16 + quad * 4 + r;
          dst[(size_t)row * 1024 + n] = f2bf(acc[i][j][r]);
        }
      }
  } else {
    const int b  = rbase >> 11;
    const int s0 = rbase & 2047;
    short* VtB = Vt + (size_t)b * 1024 * 2048;
#pragma unroll
    for (int i = 0; i < 4; ++i) {
      const int sb = s0 + i * 16 + quad * 4;
#pragma unroll
      for (int j = 0; j < 4; ++j) {
        const int d = cbase - 2048 + j * 16 + l16;
        s16x4 pk;
        pk.x = f2bf(acc[i][j][0]);
        pk.y = f2bf(acc[i][j][1]);
        pk.z = f2bf(acc[i][j][2]);
        pk.w = f2bf(acc[i][j][3]);
        *(s16x4*)(VtB + (size_t)d * 2048 + sb) = pk;
      }
    }
  }
}

// qk: 64x128 tiles, 4-wave core.  E = exp(QK^T/32) + rowsum atomics.
// Row-tile qi (64 rows, qi=0..31) needs 128-col k-tiles ki=0..(qi>>1);
// the ki==qi>>1 tile masks col>row (and zero-pads up to the 128 boundary,
// which pv never reads past (qi+1)*64).  272 tiles/batch x 4 = 1088 blocks.
// Bijective XCD chunk swizzle (1088 = 8*136): each XCD runs a contiguous
// run of the (b-major, qi-desc, ki-asc) list -> Q/K panel L2 locality.
__global__ __launch_bounds__(256) void qk_kernel(const short* __restrict__ Q,
                                                 const short* __restrict__ K,
                                                 short* __restrict__ E,
                                                 float* __restrict__ rs) {
  __shared__ short lA[4096], lB[8192];
  const int orig = blockIdx.x;
  const int g = (orig & 7) * 136 + (orig >> 3);   // 1088 = 8*136, bijective
  const int t = g >> 2;    // 0..271
  const int b = g & 3;
  int qi = 31, off = t;
  while (off >= (qi >> 1) + 1) { off -= (qi >> 1) + 1; qi--; }  // qi desc (heavy first)
  const int ki = off;

  f32x4 acc[4][2];
  const short* Qb = Q + (size_t)b * 2048 * 1024;
  const short* Kb = K + (size_t)b * 2048 * 1024;
  gemm_core64(Qb, Kb, 1024, 1024, qi * 64, ki * 128, 16, acc, lA, lB);

  const int lane = threadIdx.x & 63;
  const int wave = threadIdx.x >> 6;
  const int quad = lane >> 4;
  const int l16  = lane & 15;
  short* Eb  = E + (size_t)b * 2048 * 2048;
  float* rsb = rs + b * 2048;
  const int rbase = qi * 64;
  const int cbase = ki * 128 + wave * 32;
  const bool diag = (ki == (qi >> 1));
#pragma unroll
  for (int i = 0; i < 4; ++i)
#pragma unroll
    for (int r = 0; r < 4; ++r) {
      const int row = rbase + i * 16 + quad * 4 + r;
      float partial = 0.f;
#pragma unroll
      for (int j = 0; j < 2; ++j) {
        const int col = cbase + j * 16 + l16;
        float e = __expf(acc[i][j][r] * 0.03125f);
        if (diag && col > row) e = 0.f;
        partial += e;
        Eb[(size_t)row * 2048 + col] = f2bf(e);
      }
      partial += __shfl_xor(partial, 1);
      partial += __shfl_xor(partial, 2);
      partial += __shfl_xor(partial, 4);
      partial += __shfl_xor(partial, 8);
      if (l16 == 0) atomicAdd(rsb + row, partial);
    }
}

// pv: 64x128 out tiles, 4-wave core.  out = (E x V)/rowsum.  Row-tile qi
// (qi=0..31) has causal K-extent (qi+1)*64 -> kIters = qi+1 (E's masked
// zeros cover the diagonal remainder).  32 qi x 8 dj x 4 b = 1024 blocks
// (4/CU), bijective XCD chunk swizzle (1024 = 8*128), heavy rows first.
__global__ __launch_bounds__(256) void pv_kernel(const short* __restrict__ E,
                                                 const short* __restrict__ Vt,
                                                 const float* __restrict__ rs,
                                                 float* __restrict__ out) {
  __shared__ short lA[4096], lB[8192];
  const int orig = blockIdx.x;
  const int g = (orig & 7) * 128 + (orig >> 3);   // 1024 = 8*128, bijective
  const int t   = g >> 2;          // 0..255
  const int b   = g & 3;
  const int qi  = 31 - (t >> 3);   // heavy first
  const int dj  = t & 7;

  f32x4 acc[4][2];
  const short* Eb  = E + (size_t)b * 2048 * 2048;
  const short* Vtb = Vt + (size_t)b * 1024 * 2048;
  gemm_core64(Eb, Vtb, 2048, 2048, qi * 64, dj * 128, qi + 1, acc, lA, lB);

  const int lane = threadIdx.x & 63;
  const int wave = threadIdx.x >> 6;
  const int quad = lane >> 4;
  const int l16  = lane & 15;
  float* ob = out + (size_t)b * 2048 * 1024;
  const float* rsb = rs + b * 2048;
  const int rbase = qi * 64;
  const int cbase = dj * 128 + wave * 32;
#pragma unroll
  for (int i = 0; i < 4; ++i)
#pragma unroll
    for (int r2 = 0; r2 < 4; ++r2) {
      const int row = rbase + i * 16 + quad * 4 + r2;
      const float inv = 1.f / rsb[row];
#pragma unroll
      for (int j = 0; j < 2; ++j) {
        const int col = cbase + j * 16 + l16;
        ntst_f(&ob[(size_t)row * 1024 + col], acc[i][j][r2] * inv);
      }
    }
}

// ---------------------------------------------------------------------------
extern "C" void kernel_launch(void* const* d_in, const int* in_sizes, int n_in,
                              void* d_out, int out_size, void* d_ws, size_t ws_size,
                              hipStream_t stream) {
  const float* X = (const float*)d_in[0];
  const float* W = (const float*)d_in[1];
  float* out = (float*)d_out;
  char* w = (char*)d_ws;

  short* Xb = (short*)(w + 0);
  short* Wt = (short*)(w + 16777216);
  short* E  = (short*)(w + 0);          // overlays Xb,Wt (dead after qkv)
  float* rs = (float*)(w + 50331648);
  short* Q  = (short*)(w + 67108864);
  short* K  = (short*)(w + 83886080);
  short* Vt = (short*)(w + 100663296);

  hipLaunchKernelGGL(setup_kernel,    dim3(11272), dim3(256), 0, stream, X, W, Xb, Wt, rs);
  hipLaunchKernelGGL(qkv_gemm_kernel, dim3(1536),  dim3(256), 0, stream, Xb, Wt, Q, K, Vt);
  hipLaunchKernelGGL(qk_kernel,       dim3(1088),  dim3(256), 0, stream, Q, K, E, rs);
  hipLaunchKernelGGL(pv_kernel,       dim3(1024),  dim3(256), 0, stream, E, Vt, rs, out);
}